// Round 15
// baseline (1286.797 us; speedup 1.0000x reference)
//
#include <hip/hip_runtime.h>

#define IC 1152   // input caps
#define IS 8      // input cap size
#define OC 10     // output caps
#define OS 16     // output cap size
#define OD 160    // OC*OS
#define SQ_EPS 1e-8f
#define CPC 32    // caps per block chunk
#define NCH 36    // 1152 / 32
#define SRED_STRIDE 165

typedef _Float16 half8 __attribute__((ext_vector_type(8)));
typedef float f32x4 __attribute__((ext_vector_type(4)));

// =========================================================================
// c0_kernel: c0[cap][j] = softmax_j(bij[cap][j])  (b-independent!)
// =========================================================================
__global__ __launch_bounds__(256) void c0_kernel(const float* __restrict__ bij,
                                                 float* __restrict__ c0) {
  int cap = blockIdx.x * 256 + threadIdx.x;
  if (cap >= IC) return;
  float l[OC];
  float m = -1e30f;
#pragma unroll
  for (int j = 0; j < OC; j++) {
    l[j] = bij[cap * OC + j];
    m = fmaxf(m, l[j]);
  }
  float sum = 0.f;
#pragma unroll
  for (int j = 0; j < OC; j++) {
    l[j] = __expf(l[j] - m);
    sum += l[j];
  }
  float inv = 1.f / sum;
#pragma unroll
  for (int j = 0; j < OC; j++) c0[cap * OC + j] = l[j] * inv;
}

// =========================================================================
// prep_w: WF fragment layout for A-operand of mfma_f32_16x16x32_f16.
// lanes 0..15 hold W[cap][i][j*16+o], i=0..7 (16B per lane).
// Also writes WF0 = c0-scaled fragments (used by the pure-MFMA pass 0).
// =========================================================================
__global__ __launch_bounds__(160) void prep_w(const float* __restrict__ W,
                                              const float* __restrict__ c0,
                                              uint4* __restrict__ WF,
                                              uint4* __restrict__ WF0) {
  int cap = blockIdx.x;
  int j = threadIdx.x >> 4;
  int lp = threadIdx.x & 15;
  float cs = c0[cap * OC + j];
  union { _Float16 h[8]; uint4 u; } pk, pk0;
#pragma unroll
  for (int i = 0; i < 8; i++) {
    float w = W[(size_t)cap * (IS * OD) + i * OD + j * 16 + lp];
    pk.h[i] = (_Float16)w;
    pk0.h[i] = (_Float16)(w * cs);
  }
  WF[((size_t)cap * OC + j) * 16 + lp] = pk.u;
  WF0[((size_t)cap * OC + j) * 16 + lp] = pk0.u;
}

// =========================================================================
// pass_mfma<P0>: block = 16 b x 32 caps (4 waves, 2 caps/wave/stage,
// 4 stages of 8 caps staged in 20KB LDS). P0: pure MFMA accumulation of
// c0-scaled WF0 (no softmax). Else: per cap, uf[10] computed and KEPT LIVE
// (R4 register shape), logits from register vs4 + 2 shuffles, per-lane
// softmax, 40-FMA VALU accumulate into sacc. Epilogue: LDS-atomic sred
// reduce, then global atomicAdd into s_accum[b][160].
// LDS = 20 + 8 + 10.56 = 38.6 KB -> 4 blocks/CU; VGPR forced <=128.
// =========================================================================
template <bool P0>
__global__ __launch_bounds__(256, 4) void pass_mfma(
    const float* __restrict__ x, const uint4* __restrict__ WFsrc,
    const float* __restrict__ bij, const float* __restrict__ Vsum,
    float* __restrict__ s_accum, int Bn) {
  int b0 = blockIdx.x * 16;
  int ch = blockIdx.y;
  int cap0 = ch * CPC;
  int tid = threadIdx.x;
  int wid = tid >> 6;
  int lane = tid & 63;
  int bl = lane & 15;        // b column this lane owns
  int og = (lane >> 4) * 4;  // o-quad base of this lane's C rows
  int gb = b0 + bl;
  bool bok = gb < Bn;

  __shared__ __align__(16) uint4 WFl[8 * 160];   // 20 KB: one 8-cap stage
  __shared__ __align__(16) uint4 xlh[CPC * 16];  // 8 KB f16-packed x
  __shared__ float sred[16 * SRED_STRIDE];       // 10.56 KB

  for (int e = tid; e < 16 * SRED_STRIDE; e += 256) sred[e] = 0.f;

  // ---- stage x tile (32 caps x 16 b) as packed f16, XOR-swizzled on b ----
  for (int e = tid; e < CPC * 16; e += 256) {
    int cc = e & (CPC - 1), bb = e >> 5;
    int b = b0 + bb;
    float xf[8] = {0, 0, 0, 0, 0, 0, 0, 0};
    if (b < Bn) {
      *(float4*)&xf[0] = *(const float4*)&x[((size_t)b * IC + cap0 + cc) * IS];
      *(float4*)&xf[4] =
          *(const float4*)&x[((size_t)b * IC + cap0 + cc) * IS + 4];
    }
    union { _Float16 h[8]; uint4 u; } pk;
#pragma unroll
    for (int s = 0; s < 8; s++) pk.h[s] = (_Float16)xf[s];
    xlh[cc * 16 + (bb ^ (cc & 15))] = pk.u;
  }

  // ---- stage WFl for stage 0 (caps cap0 .. cap0+7): 1280 uint4 ----
  {
    const uint4* src = WFsrc + (size_t)cap0 * 160;
#pragma unroll
    for (int k = 0; k < 5; k++) WFl[k * 256 + tid] = src[k * 256 + tid];
  }
  __syncthreads();

  // ---- Vsum slice for this lane (loop-invariant registers) ----
  f32x4 vs4[OC];
#pragma unroll
  for (int j = 0; j < OC; j++) vs4[j] = (f32x4){0.f, 0.f, 0.f, 0.f};
  if (!P0 && bok) {
    const float* vrow = Vsum + (size_t)gb * OD;
#pragma unroll
    for (int j = 0; j < OC; j++) {
      float4 t = *(const float4*)(vrow + j * 16 + og);
      vs4[j] = (f32x4){t.x, t.y, t.z, t.w};
    }
  }

  f32x4 sacc[OC];
#pragma unroll
  for (int j = 0; j < OC; j++) sacc[j] = (f32x4){0.f, 0.f, 0.f, 0.f};

  for (int s = 0; s < 4; ++s) {
    if (s > 0) {
      __syncthreads();  // everyone done reading previous stage
      const uint4* src = WFsrc + ((size_t)cap0 + (size_t)s * 8) * 160;
#pragma unroll
      for (int k = 0; k < 5; k++) WFl[k * 256 + tid] = src[k * 256 + tid];
      __syncthreads();  // stage s visible
    }

    // wave wid handles caps idx = wid*2, wid*2+1 of this stage
#pragma unroll
    for (int c = 0; c < 2; ++c) {
      int idx = wid * 2 + c;   // cap within stage (0..7), wave-uniform
      int cc = s * 8 + idx;    // cap within chunk (0..31)
      int cap = cap0 + cc;

      // B-operand (x): lanes 0..15 real, others zero => A k>=8 junk nulled
      union { uint4 u; half8 h; } xb;
      xb.u = xlh[cc * 16 + (bl ^ (cc & 15))];
      if (lane >= 16) xb.u = make_uint4(0, 0, 0, 0);

      if (P0) {
        // pure MFMA accumulation (c0 pre-folded into WF0)
#pragma unroll
        for (int j = 0; j < OC; j++) {
          union { uint4 u; half8 h; } wa;
          wa.u = WFl[idx * 160 + j * 16 + bl];
          sacc[j] = __builtin_amdgcn_mfma_f32_16x16x32_f16(wa.h, xb.h, sacc[j],
                                                           0, 0, 0);
        }
      } else {
        // uf[10] live (R4 register shape)
        f32x4 uf[OC];
#pragma unroll
        for (int j = 0; j < OC; j++) {
          union { uint4 u; half8 h; } wa;
          wa.u = WFl[idx * 160 + j * 16 + bl];
          f32x4 z = {0.f, 0.f, 0.f, 0.f};
          uf[j] =
              __builtin_amdgcn_mfma_f32_16x16x32_f16(wa.h, xb.h, z, 0, 0, 0);
        }

        float l[OC];
#pragma unroll
        for (int j = 0; j < OC; j++) {
          float t = uf[j].x * vs4[j].x + uf[j].y * vs4[j].y +
                    uf[j].z * vs4[j].z + uf[j].w * vs4[j].w;
          t += __shfl_xor(t, 16, 64);
          t += __shfl_xor(t, 32, 64);
          l[j] = bij[cap * OC + j] + t;
        }
        float m = l[0];
#pragma unroll
        for (int j = 1; j < OC; j++) m = fmaxf(m, l[j]);
        float sum = 0.f;
#pragma unroll
        for (int j = 0; j < OC; j++) {
          l[j] = __expf(l[j] - m);
          sum += l[j];
        }
        float inv = 1.f / sum;
#pragma unroll
        for (int j = 0; j < OC; j++) {
          float cj = l[j] * inv;
          sacc[j].x += cj * uf[j].x;
          sacc[j].y += cj * uf[j].y;
          sacc[j].z += cj * uf[j].z;
          sacc[j].w += cj * uf[j].w;
        }
      }
    }
  }

  // ---- cross-wave reduce via LDS float atomics ----
  float* sw = &sred[bl * SRED_STRIDE];
#pragma unroll
  for (int j = 0; j < OC; j++) {
    atomicAdd(&sw[j * 16 + og + 0], sacc[j].x);
    atomicAdd(&sw[j * 16 + og + 1], sacc[j].y);
    atomicAdd(&sw[j * 16 + og + 2], sacc[j].z);
    atomicAdd(&sw[j * 16 + og + 3], sacc[j].w);
  }
  __syncthreads();

  // ---- block partial -> global atomic accumulate (L2-resident target) ----
  for (int e = tid; e < 16 * OD; e += 256) {
    int bb = e / OD, d = e - bb * OD;
    int g = b0 + bb;
    if (g < Bn) atomicAdd(&s_accum[(size_t)g * OD + d], sred[bb * SRED_STRIDE + d]);
  }
}

// =========================================================================
// reduce_squash: read s_accum[b], re-zero for next pass, squash,
// update Vsum (mode 0: =, 1: +=) or write output (mode 2).
// =========================================================================
__global__ __launch_bounds__(192) void reduce_squash(
    float* __restrict__ s_accum, float* __restrict__ Vsum,
    float* __restrict__ out, int mode) {
  int b = blockIdx.x;
  int tid = threadIdx.x;
  __shared__ float sl[OD];
  __shared__ float sc[OC];
  if (tid < OD) {
    float s = s_accum[(size_t)b * OD + tid];
    s_accum[(size_t)b * OD + tid] = 0.f;  // re-zero for next pass
    sl[tid] = s;
  }
  __syncthreads();
  if (tid < OC) {
    float sq = 0.f;
#pragma unroll
    for (int d = 0; d < OS; d++) {
      float v = sl[tid * OS + d];
      sq += v * v;
    }
    sc[tid] = (sq / (1.f + sq)) / sqrtf(sq + SQ_EPS);
  }
  __syncthreads();
  if (tid < OD) {
    float v = sl[tid] * sc[tid >> 4];
    if (mode == 2)
      out[(size_t)b * OD + tid] = v;
    else if (mode == 0)
      Vsum[(size_t)b * OD + tid] = v;
    else
      Vsum[(size_t)b * OD + tid] += v;
  }
}

// =========================================================================
// Monolithic fallback (tiny ws) — proven correct path.
// =========================================================================
__global__ __launch_bounds__(256) void routing_fallback(
    const float* __restrict__ x, const float* __restrict__ W,
    const float* __restrict__ bij, float* __restrict__ out) {
  int b = blockIdx.x;
  int tid = threadIdx.x;
  int wid = tid >> 6;
  int lane = tid & 63;
  int dq = lane & 3;
  int slot = wid * 16 + (lane >> 2);

  __shared__ __align__(16) float Vs[OD];
  __shared__ __align__(16) float sred2[4][OD];
  __shared__ float sc[OC];

  if (tid < OD) Vs[tid] = 0.f;
  __syncthreads();

  for (int pass = 0; pass < 4; ++pass) {
    float4 vsr[OC];
#pragma unroll
    for (int j = 0; j < OC; j++) vsr[j] = *(const float4*)&Vs[j * 16 + dq * 4];
    float4 sp[OC];
#pragma unroll
    for (int j = 0; j < OC; j++) sp[j] = make_float4(0.f, 0.f, 0.f, 0.f);

    for (int r = 0; r < IC / 64; ++r) {
      int cap = r * 64 + slot;
      float xr[8];
#pragma unroll
      for (int s = 0; s < 8; s++) xr[s] = x[((size_t)b * IC + cap) * IS + s];
      float4 u[OC];
#pragma unroll
      for (int j = 0; j < OC; j++) {
        float4 acc = make_float4(0.f, 0.f, 0.f, 0.f);
#pragma unroll
        for (int s = 0; s < 8; s++) {
          const float4 w =
              *(const float4*)&W[((size_t)cap * IS + s) * OD + j * 16 + dq * 4];
          acc.x += xr[s] * w.x;
          acc.y += xr[s] * w.y;
          acc.z += xr[s] * w.z;
          acc.w += xr[s] * w.w;
        }
        u[j] = acc;
      }
      float l[OC];
#pragma unroll
      for (int j = 0; j < OC; j++) {
        float a = u[j].x * vsr[j].x + u[j].y * vsr[j].y + u[j].z * vsr[j].z +
                  u[j].w * vsr[j].w;
        a += __shfl_xor(a, 1, 64);
        a += __shfl_xor(a, 2, 64);
        l[j] = bij[cap * OC + j] + a;
      }
      float m = l[0];
#pragma unroll
      for (int j = 1; j < OC; j++) m = fmaxf(m, l[j]);
      float sum = 0.f, c[OC];
#pragma unroll
      for (int j = 0; j < OC; j++) {
        c[j] = __expf(l[j] - m);
        sum += c[j];
      }
      float inv = 1.f / sum;
#pragma unroll
      for (int j = 0; j < OC; j++) {
        float ccv = c[j] * inv;
        sp[j].x += ccv * u[j].x;
        sp[j].y += ccv * u[j].y;
        sp[j].z += ccv * u[j].z;
        sp[j].w += ccv * u[j].w;
      }
    }
#pragma unroll
    for (int mask = 4; mask <= 32; mask <<= 1) {
#pragma unroll
      for (int j = 0; j < OC; j++) {
        sp[j].x += __shfl_xor(sp[j].x, mask, 64);
        sp[j].y += __shfl_xor(sp[j].y, mask, 64);
        sp[j].z += __shfl_xor(sp[j].z, mask, 64);
        sp[j].w += __shfl_xor(sp[j].w, mask, 64);
      }
    }
    if (lane < 4) {
#pragma unroll
      for (int j = 0; j < OC; j++)
        *(float4*)&sred2[wid][j * 16 + dq * 4] = sp[j];
    }
    __syncthreads();
    if (tid < OD) {
      float s = sred2[0][tid] + sred2[1][tid] + sred2[2][tid] + sred2[3][tid];
      sred2[0][tid] = s;
    }
    __syncthreads();
    if (tid < OC) {
      float sq = 0.f;
#pragma unroll
      for (int d = 0; d < OS; d++) {
        float v = sred2[0][tid * OS + d];
        sq += v * v;
      }
      sc[tid] = (sq / (1.f + sq)) / sqrtf(sq + SQ_EPS);
    }
    __syncthreads();
    if (tid < OD) {
      float vv = sred2[0][tid] * sc[tid >> 4];
      if (pass < 3)
        Vs[tid] += vv;
      else
        out[(size_t)b * OD + tid] = vv;
    }
    __syncthreads();
  }
}

// =========================================================================
extern "C" void kernel_launch(void* const* d_in, const int* in_sizes, int n_in,
                              void* d_out, int out_size, void* d_ws,
                              size_t ws_size, hipStream_t stream) {
  const float* x = (const float*)d_in[0];    // (B, 1152, 8)
  const float* W = (const float*)d_in[1];    // (1152, 8, 160)
  const float* bij = (const float*)d_in[2];  // (1152, 10)
  float* out = (float*)d_out;                // (B, 10, 16)

  int Bn = in_sizes[0] / (IC * IS);
  size_t buf = (size_t)Bn * OD * sizeof(float);
  size_t wf_bytes = (size_t)IC * OC * 16 * 16;        // 2.95 MB
  size_t c0_bytes = (size_t)IC * OC * sizeof(float);  // 46 KB

  if (ws_size >= 2 * wf_bytes + c0_bytes + 2 * buf) {
    uint4* WF = (uint4*)d_ws;
    uint4* WF0 = (uint4*)((char*)d_ws + wf_bytes);
    float* c0 = (float*)((char*)d_ws + 2 * wf_bytes);
    float* s_accum = (float*)((char*)d_ws + 2 * wf_bytes + c0_bytes);
    float* Vs = (float*)((char*)d_ws + 2 * wf_bytes + c0_bytes + buf);

    c0_kernel<<<(IC + 255) / 256, 256, 0, stream>>>(bij, c0);
    prep_w<<<IC, 160, 0, stream>>>(W, c0, WF, WF0);
    hipMemsetAsync(s_accum, 0, buf, stream);

    dim3 pg((Bn + 15) / 16, NCH);
    // pass 0: coupling = softmax(b_ij) folded into WF0 -> pure MFMA
    pass_mfma<true><<<pg, 256, 0, stream>>>(x, WF0, bij, nullptr, s_accum, Bn);
    reduce_squash<<<Bn, 192, 0, stream>>>(s_accum, Vs, out, 0);
    // passes 1-3: full routing (uf-live, LDS-W, 4-blocks/CU)
    pass_mfma<false><<<pg, 256, 0, stream>>>(x, WF, bij, Vs, s_accum, Bn);
    reduce_squash<<<Bn, 192, 0, stream>>>(s_accum, Vs, out, 1);
    pass_mfma<false><<<pg, 256, 0, stream>>>(x, WF, bij, Vs, s_accum, Bn);
    reduce_squash<<<Bn, 192, 0, stream>>>(s_accum, Vs, out, 1);
    pass_mfma<false><<<pg, 256, 0, stream>>>(x, WF, bij, Vs, s_accum, Bn);
    reduce_squash<<<Bn, 192, 0, stream>>>(s_accum, Vs, out, 2);
  } else {
    routing_fallback<<<Bn, 256, 0, stream>>>(x, W, bij, out);
  }
}